// Round 8
// baseline (764.575 us; speedup 1.0000x reference)
//
#include <hip/hip_runtime.h>
#include <math.h>

// Problem dims
#define BDIM 1024
#define RDIM 1152
#define IDIM 8
#define CDIM 10
#define ODIM 16
#define CO   160   // CDIM*ODIM

typedef _Float16 half_t;
typedef half_t f16x4 __attribute__((ext_vector_type(4)));
typedef half_t f16x8 __attribute__((ext_vector_type(8)));
typedef float  f32x4 __attribute__((ext_vector_type(4)));

constexpr int RSPLIT = 16;                      // r splits in k_s
constexpr int R_PER_SPLIT = RDIM / RSPLIT;      // 72
constexpr int CH_R = 8;                         // r chunk per stage (2 MFMA k-steps)

// workspace layout (in float units)
// bl is stored TRANSPOSED: (C, B, R)  -> k_b writes r-runs, k_stats reads contiguous rows
constexpr size_t OFF_BL = 0;
constexpr size_t SZ_BL  = (size_t)BDIM * RDIM * CDIM;         // 11,796,480
constexpr size_t OFF_V  = OFF_BL + SZ_BL;                     // v (B,C,O)
constexpr size_t SZ_V   = (size_t)BDIM * CO;
constexpr size_t OFF_ST = OFF_V + SZ_V;                       // stats (B,C,2): max, 1/sumexp
constexpr size_t SZ_ST  = (size_t)BDIM * CDIM * 2;
constexpr size_t OFF_SP = OFF_ST + SZ_ST;                     // s partials (RSPLIT,B,C,O)
constexpr size_t SZ_SP  = (size_t)RSPLIT * BDIM * CO;
constexpr size_t OFF_WF = OFF_SP + SZ_SP;                     // k_s W frags (f16)
constexpr size_t SZ_WF  = 737280;                             // 184320*8 f16
constexpr size_t OFF_WB = OFF_WF + SZ_WF;                     // k_b W frags (f16)
constexpr size_t SZ_WB  = 737280;                             // [R][C][16 lanes][8 i] f16
// total: 16,076,800 floats = 64.3 MB

// ---------------------------------------------------------------------------
// k_wprep: W (R,I,C,O) f32 -> fragment-ordered f16 for k_s's B operand (K=32).
// WF[((rq*10+c)*64+l)*8 + j] = (f16) W[rq*4 + (l>>4)][i=j][c][o=l&15]
// ---------------------------------------------------------------------------
__global__ __launch_bounds__(256) void k_wprep(const float* __restrict__ W,
                                               half_t* __restrict__ WF) {
    int g = blockIdx.x * 256 + threadIdx.x;    // 184320
    int lane = g & 63;
    int rc = g >> 6;
    int c = rc % 10;
    int rq = rc / 10;
    int r = rq * 4 + (lane >> 4);
    int o = lane & 15;
    const float* wp = W + (size_t)r * IDIM * CO + c * ODIM + o;
    f16x8 v;
#pragma unroll
    for (int j = 0; j < 8; ++j) v[j] = (half_t)wp[(size_t)j * CO];
    *(f16x8*)(WF + (size_t)g * 8) = v;
}

// ---------------------------------------------------------------------------
// k_wprep_b: W -> per-(r,c) B-frag for k_b's K=32 mfma (only k=0..7 live).
// WB[((r*10+c)*16 + l)*8 + j] = (f16) W[r][i=j][c][o=l],  l = 0..15
// ---------------------------------------------------------------------------
__global__ __launch_bounds__(256) void k_wprep_b(const float* __restrict__ W,
                                                 half_t* __restrict__ WB) {
    int g = blockIdx.x * 256 + threadIdx.x;    // 184320
    int l = g & 15;
    int rc = g >> 4;
    int c = rc % 10;
    int r = rc / 10;
    const float* wp = W + ((size_t)r * 80 + c) * 16 + l;   // W[(r*8+j)*160 + c*16 + o]
    f16x8 v;
#pragma unroll
    for (int j = 0; j < 8; ++j) v[j] = (half_t)wp[(size_t)j * CO];
    *(f16x8*)(WB + (size_t)g * 8) = v;
}

// ---------------------------------------------------------------------------
// k_s_mfma: s_part[split][b][c][o] = sum_{r in split} cval(b,r,c)*u_hat(b,r,c,o)
// (unchanged core from R7; cvl staging adapted to bl layout (C,B,R))
// ---------------------------------------------------------------------------
template <int MODE>
__global__ __launch_bounds__(256) void k_s_mfma(const float* __restrict__ x,
                                                const half_t* __restrict__ WF,
                                                const float* __restrict__ bl,
                                                const float* __restrict__ stats,
                                                float* __restrict__ s_part) {
    __shared__ half_t xs[CH_R * 32 * IDIM];     // [rr][bb][i] f16, 4 KB
    __shared__ float cvl[CH_R * 32 * CDIM];     // [rr][bb][cc] f32, 10 KB
    __shared__ float sts[32 * CDIM * 2];        // stats tile, 2.5 KB
    const int t = threadIdx.x;
    const int l = t & 63, w = t >> 6;
    const int b0 = blockIdx.x * 32;
    const int rg0 = blockIdx.y * R_PER_SPLIT;
    const int cbase = (w & 1) * 5;
    const int bsub = w >> 1;
    const int row = l & 15;
    const int kg = l >> 4;

    if (MODE == 1) {
        for (int e = t; e < 32 * CDIM * 2; e += 256)
            sts[e] = stats[(size_t)b0 * CDIM * 2 + e];
    }
    __syncthreads();

    f32x4 acc[5];
#pragma unroll
    for (int s = 0; s < 5; ++s) acc[s] = (f32x4){0.f, 0.f, 0.f, 0.f};

    for (int ch = 0; ch < R_PER_SPLIT / CH_R; ++ch) {
        const int r0c = rg0 + ch * CH_R;
        for (int e = t; e < 512; e += 256) {
            int rr = e >> 6, rem = e & 63, bb = rem >> 1, q = rem & 1;
            const float4 x4 = *(const float4*)(
                x + ((size_t)(b0 + bb) * RDIM + r0c + rr) * IDIM + q * 4);
            f16x4 h;
            h[0] = (half_t)x4.x; h[1] = (half_t)x4.y;
            h[2] = (half_t)x4.z; h[3] = (half_t)x4.w;
            *(f16x4*)&xs[(rr * 32 + bb) * IDIM + q * 4] = h;
        }
        if (MODE == 1) {
            // bl layout (C,B,R): 8 consecutive r per (bb,cc)
            for (int e = t; e < CH_R * 32 * CDIM; e += 256) {
                int bb = e / 80;
                int rem = e - bb * 80;
                int cc = rem >> 3, rr = rem & 7;
                float bv = bl[((size_t)cc * BDIM + b0 + bb) * RDIM + r0c + rr];
                cvl[(rr * 32 + bb) * CDIM + cc] =
                    __expf(bv - sts[bb * 20 + cc * 2]) * sts[bb * 20 + cc * 2 + 1];
            }
        }
        __syncthreads();

#pragma unroll
        for (int rq = 0; rq < CH_R / 4; ++rq) {
            const int rr = rq * 4 + kg;
            const f16x8 xv = *(const f16x8*)&xs[(rr * 32 + bsub * 16 + row) * IDIM];
            const int rqg = (r0c >> 2) + rq;
#pragma unroll
            for (int s = 0; s < 5; ++s) {
                const int cc = cbase + s;
                float cval = (MODE == 1)
                    ? cvl[(rr * 32 + bsub * 16 + row) * CDIM + cc] : 1.0f;
                half_t chf = (half_t)cval;
                f16x8 av;
#pragma unroll
                for (int j = 0; j < 8; ++j) av[j] = xv[j] * chf;
                const f16x8 bv = *(const f16x8*)(
                    WF + ((size_t)(rqg * CDIM + cc) * 64 + l) * 8);
                acc[s] = __builtin_amdgcn_mfma_f32_16x16x32_f16(av, bv, acc[s], 0, 0, 0);
            }
        }
        __syncthreads();
    }

#pragma unroll
    for (int s = 0; s < 5; ++s) {
        const int cc = cbase + s;
#pragma unroll
        for (int reg = 0; reg < 4; ++reg) {
            float val = acc[s][reg];
            if (MODE == 0) val *= (1.0f / RDIM);
            int brow = b0 + bsub * 16 + kg * 4 + reg;
            s_part[((size_t)blockIdx.y * BDIM + brow) * CO + cc * ODIM + (l & 15)] = val;
        }
    }
}

// ---------------------------------------------------------------------------
// k_squash: s = sum over partials; v = (n/(n+1)) * s / sqrt(n)
// ---------------------------------------------------------------------------
__global__ __launch_bounds__(256) void k_squash(const float* __restrict__ s_part,
                                                float* __restrict__ dst) {
    int g = blockIdx.x * 256 + threadIdx.x;
    int b = g / CO;
    int co = g - b * CO;
    float s = 0.f;
#pragma unroll
    for (int p = 0; p < RSPLIT; ++p)
        s += s_part[((size_t)p * BDIM + b) * CO + co];
    float sq = s * s;
    sq += __shfl_xor(sq, 1, 16);
    sq += __shfl_xor(sq, 2, 16);
    sq += __shfl_xor(sq, 4, 16);
    sq += __shfl_xor(sq, 8, 16);
    float n = sq;
    float val = (n / (n + 1.0f)) * s / sqrtf(n);
    dst[g] = val;
}

// ---------------------------------------------------------------------------
// k_b_mfma: bl[c][b][r] (+)= sum_o u_hat(b,r,c,o) * v[b,c,o]
// u_hat via mfma_f32_16x16x32_f16 (K: k<8 = i, k>=8 zeroed on A side).
// Block 256 thr = 4 waves; wave w owns b16 sub-tile; r-tile 32; all 10 c.
// o-contraction: 4 muls by hoisted v regs + width-16 shfl reduce.
// Wave-local [32r][17] LDS tile transposes for coalesced (C,B,R) writes.
// ---------------------------------------------------------------------------
template <int ACC>
__global__ __launch_bounds__(256) void k_b_mfma(const float* __restrict__ x,
                                                const half_t* __restrict__ WB,
                                                const float* __restrict__ v,
                                                float* __restrict__ bl) {
    __shared__ half_t xs[32][520];   // [r][b*8+i], row 1040 B (pad kills write conflicts)
    __shared__ float tt[4][32][17];  // per-wave transpose tile (17 coprime 32)
    const int t = threadIdx.x, l = t & 63, w = t >> 6;
    const int b0 = blockIdx.x * 64, r0 = blockIdx.y * 32;
    const int kg = l >> 4, row = l & 15;
    const int bw = w * 16;

    // stage x tile: 64 b x 32 r x 8 i  (f32 -> f16), coalesced 1 KB runs per b
    for (int e = t; e < 4096; e += 256) {
        int b = e >> 6, k = e & 63, r = k >> 1, q = (k & 1) * 4;
        const float4 x4 = *(const float4*)(
            x + ((size_t)(b0 + b) * RDIM + r0 + r) * IDIM + q);
        f16x4 h;
        h[0] = (half_t)x4.x; h[1] = (half_t)x4.y;
        h[2] = (half_t)x4.z; h[3] = (half_t)x4.w;
        *(f16x4*)&xs[r][b * 8 + q] = h;
    }

    // hoist v: lane's (b = bw+kg*4+reg, o = row) for all 10 c  -> 40 VGPR
    float vv[10][4];
#pragma unroll
    for (int c = 0; c < 10; ++c)
#pragma unroll
        for (int reg = 0; reg < 4; ++reg)
            vv[c][reg] = v[(size_t)(b0 + bw + kg * 4 + reg) * CO + c * ODIM + row];

    __syncthreads();

    for (int c = 0; c < 10; ++c) {
        for (int r = 0; r < 32; ++r) {
            f16x8 a = {0, 0, 0, 0, 0, 0, 0, 0};
            if (kg == 0)   // A: row=l&15 (b), k=j (i); k>=8 zero
                a = *(const f16x8*)&xs[r][(bw + row) * 8];
            // B-frag: only kg==0 lanes matter (A zero elsewhere); dup via row
            const f16x8 bf = *(const f16x8*)(
                WB + (((size_t)(r0 + r) * CDIM + c) * 16 + row) * 8);
            f32x4 acc = {0.f, 0.f, 0.f, 0.f};
            acc = __builtin_amdgcn_mfma_f32_16x16x32_f16(a, bf, acc, 0, 0, 0);
            // D: col(o)=l&15, row(b)=kg*4+reg. Dot with v over o via shfl.
#pragma unroll
            for (int reg = 0; reg < 4; ++reg) {
                float pv = acc[reg] * vv[c][reg];
                pv += __shfl_xor(pv, 1, 16);
                pv += __shfl_xor(pv, 2, 16);
                pv += __shfl_xor(pv, 4, 16);
                pv += __shfl_xor(pv, 8, 16);
                if (row == 0) tt[w][r][kg * 4 + reg] = pv;
            }
        }
        // copy-out: [32r][16b] -> bl[c][b][r], 2x128B runs per pass
        const size_t gbase = (size_t)c * BDIM + b0 + bw;
#pragma unroll
        for (int pp = 0; pp < 8; ++pp) {
            int bb = pp * 2 + (l >> 5);
            int rr = l & 31;
            float val = tt[w][rr][bb];
            size_t gi = (gbase + bb) * RDIM + r0 + rr;
            if (ACC) val += bl[gi];
            bl[gi] = val;
        }
    }
}

// ---------------------------------------------------------------------------
// k_stats: per (b,c): max over r of bl[c][b][:], and 1/sum(exp(.-max)).
// One wave per (b,c); 1152 = 18*64 contiguous floats.
// ---------------------------------------------------------------------------
__global__ __launch_bounds__(256) void k_stats(const float* __restrict__ bl,
                                               float* __restrict__ stats) {
    const int t = threadIdx.x, lane = t & 63, w = t >> 6;
    const int gw = blockIdx.x * 4 + w;          // b*10 + c, 0..10239
    const int b = gw / 10, c = gw - b * 10;
    const float* p = bl + ((size_t)c * BDIM + b) * RDIM;
    float rv[18];
#pragma unroll
    for (int s = 0; s < 18; ++s) rv[s] = p[lane + s * 64];
    float m = rv[0];
#pragma unroll
    for (int s = 1; s < 18; ++s) m = fmaxf(m, rv[s]);
    for (int d = 1; d < 64; d <<= 1) m = fmaxf(m, __shfl_xor(m, d, 64));
    float se = 0.f;
#pragma unroll
    for (int s = 0; s < 18; ++s) se += __expf(rv[s] - m);
    for (int d = 1; d < 64; d <<= 1) se += __shfl_xor(se, d, 64);
    if (lane == 0) {
        stats[(size_t)gw * 2 + 0] = m;
        stats[(size_t)gw * 2 + 1] = 1.0f / se;
    }
}

// ---------------------------------------------------------------------------
extern "C" void kernel_launch(void* const* d_in, const int* in_sizes, int n_in,
                              void* d_out, int out_size, void* d_ws, size_t ws_size,
                              hipStream_t stream) {
    const float* x = (const float*)d_in[0];
    const float* W = (const float*)d_in[1];
    float* out = (float*)d_out;
    float* ws = (float*)d_ws;

    float* bl = ws + OFF_BL;
    float* v  = ws + OFF_V;
    float* st = ws + OFF_ST;
    float* sp = ws + OFF_SP;
    half_t* wf = (half_t*)(ws + OFF_WF);
    half_t* wb = (half_t*)(ws + OFF_WB);

    dim3 gs(BDIM / 32, RSPLIT);                // 32 x 16 blocks of 256
    dim3 gb(BDIM / 64, RDIM / 32);             // 16 x 36 blocks of 256

    k_wprep<<<720, 256, 0, stream>>>(W, wf);
    k_wprep_b<<<720, 256, 0, stream>>>(W, wb);

    // iteration 0: softmax(0) uniform -> s0 = mean_r u_hat
    k_s_mfma<0><<<gs, 256, 0, stream>>>(x, wf, bl, st, sp);
    k_squash<<<(BDIM * CO) / 256, 256, 0, stream>>>(sp, v);
    k_b_mfma<0><<<gb, 256, 0, stream>>>(x, wb, v, bl);     // b1 = u_hat . v0

    // iteration 1
    k_stats<<<2560, 256, 0, stream>>>(bl, st);
    k_s_mfma<1><<<gs, 256, 0, stream>>>(x, wf, bl, st, sp);
    k_squash<<<(BDIM * CO) / 256, 256, 0, stream>>>(sp, v);
    k_b_mfma<1><<<gb, 256, 0, stream>>>(x, wb, v, bl);     // b2 = b1 + u_hat . v1

    // iteration 2 (final; no b update)
    k_stats<<<2560, 256, 0, stream>>>(bl, st);
    k_s_mfma<1><<<gs, 256, 0, stream>>>(x, wf, bl, st, sp);
    k_squash<<<(BDIM * CO) / 256, 256, 0, stream>>>(sp, out);
}

// Round 10
// 337.127 us; speedup vs baseline: 2.2679x; 2.2679x over previous
//
#include <hip/hip_runtime.h>
#include <math.h>

// Problem dims
#define BDIM 1024
#define RDIM 1152
#define IDIM 8
#define CDIM 10
#define ODIM 16
#define CO   160   // CDIM*ODIM

typedef _Float16 half_t;
typedef half_t f16x4 __attribute__((ext_vector_type(4)));
typedef half_t f16x8 __attribute__((ext_vector_type(8)));
typedef float  f32x4 __attribute__((ext_vector_type(4)));

constexpr int RSPLIT = 16;                      // r splits in k_s
constexpr int R_PER_SPLIT = RDIM / RSPLIT;      // 72
constexpr int CH_R = 8;                         // r chunk per stage (2 MFMA k-steps)

// workspace layout (in float units)
// bl stored TRANSPOSED: (C, B, R) -> k_bT writes r-runs, k_stats reads rows
constexpr size_t OFF_BL = 0;
constexpr size_t SZ_BL  = (size_t)BDIM * RDIM * CDIM;         // 11,796,480
constexpr size_t OFF_V  = OFF_BL + SZ_BL;                     // v (B,C,O)
constexpr size_t SZ_V   = (size_t)BDIM * CO;
constexpr size_t OFF_ST = OFF_V + SZ_V;                       // stats (B,C,2)
constexpr size_t SZ_ST  = (size_t)BDIM * CDIM * 2;
constexpr size_t OFF_SP = OFF_ST + SZ_ST;                     // s partials
constexpr size_t SZ_SP  = (size_t)RSPLIT * BDIM * CO;
constexpr size_t OFF_WF = OFF_SP + SZ_SP;                     // k_s W frags (f16)
constexpr size_t SZ_WF  = 737280;                             // 184320*8 f16
constexpr size_t OFF_WA = OFF_WF + SZ_WF;                     // k_bT A frags (f16)
constexpr size_t SZ_WA  = 1474560;                            // 368640*8 f16 / 2
constexpr size_t OFF_VF = OFF_WA + SZ_WA;                     // k_bT B frags (f16)
constexpr size_t SZ_VF  = 163840;                             // 40960*8 f16 / 2
// total ~16.98M floats = 67.9 MB

// ---------------------------------------------------------------------------
// k_wprep: W (R,I,C,O) f32 -> fragment-ordered f16 for k_s's B operand (K=32).
// WF[((rq*10+c)*64+l)*8 + j] = (f16) W[rq*4 + (l>>4)][i=j][c][o=l&15]
// ---------------------------------------------------------------------------
__global__ __launch_bounds__(256) void k_wprep(const float* __restrict__ W,
                                               half_t* __restrict__ WF) {
    int g = blockIdx.x * 256 + threadIdx.x;    // 184320
    int lane = g & 63;
    int rc = g >> 6;
    int c = rc % 10;
    int rq = rc / 10;
    int r = rq * 4 + (lane >> 4);
    int o = lane & 15;
    const float* wp = W + (size_t)r * IDIM * CO + c * ODIM + o;
    f16x8 v;
#pragma unroll
    for (int j = 0; j < 8; ++j) v[j] = (half_t)wp[(size_t)j * CO];
    *(f16x8*)(WF + (size_t)g * 8) = v;
}

// ---------------------------------------------------------------------------
// k_wprep_T: A-frags for k_bT's T-GEMM.  A[m=(r,i)][k=o] per c, K padded to 32.
// WA[((mt*10+c)*64 + l)*8 + j]:
//   row = l&15, m = mt*16+row, r = m>>3, i = m&7, kg = l>>4
//   kg<2: (f16) W[r][i][c][o=kg*8+j] ; kg>=2: 0
// ---------------------------------------------------------------------------
__global__ __launch_bounds__(256) void k_wprep_T(const float* __restrict__ W,
                                                 half_t* __restrict__ WA) {
    int g = blockIdx.x * 256 + threadIdx.x;    // 576*10*64 = 368640
    int l = g & 63;
    int mc = g >> 6;
    int c = mc % 10;
    int mt = mc / 10;
    int m = mt * 16 + (l & 15);
    int r = m >> 3, i = m & 7, kg = l >> 4;
    f16x8 v = {0, 0, 0, 0, 0, 0, 0, 0};
    if (kg < 2) {
        const float* wp = W + (size_t)r * 1280 + i * 160 + c * 16 + kg * 8;
#pragma unroll
        for (int j = 0; j < 8; ++j) v[j] = (half_t)wp[j];
    }
    *(f16x8*)(WA + (size_t)g * 8) = v;
}

// ---------------------------------------------------------------------------
// k_vprep: B-frags for k_bT.  B[k=o][n=b] per (c, b-tile), K padded to 32.
// VF[((c*64+bt)*64 + l)*8 + j]: l<32: (f16) v[bt*16+(l&15)][c][o=(l>>4)*8+j]; else 0
// ---------------------------------------------------------------------------
__global__ __launch_bounds__(256) void k_vprep(const float* __restrict__ v,
                                               half_t* __restrict__ VF) {
    int g = blockIdx.x * 256 + threadIdx.x;    // 10*64*64 = 40960
    int l = g & 63;
    int cb = g >> 6;
    int bt = cb & 63;
    int c = cb >> 6;
    f16x8 h = {0, 0, 0, 0, 0, 0, 0, 0};
    if (l < 32) {
        const float* vp = v + (size_t)(bt * 16 + (l & 15)) * CO + c * 16 + (l >> 4) * 8;
#pragma unroll
        for (int j = 0; j < 8; ++j) h[j] = (half_t)vp[j];
    }
    *(f16x8*)(VF + (size_t)g * 8) = h;
}

// ---------------------------------------------------------------------------
// k_s_mfma: s_part[split][b][c][o] = sum_{r in split} cval(b,r,c)*u_hat(b,r,c,o)
// ---------------------------------------------------------------------------
template <int MODE>
__global__ __launch_bounds__(256) void k_s_mfma(const float* __restrict__ x,
                                                const half_t* __restrict__ WF,
                                                const float* __restrict__ bl,
                                                const float* __restrict__ stats,
                                                float* __restrict__ s_part) {
    __shared__ half_t xs[CH_R * 32 * IDIM];     // [rr][bb][i] f16, 4 KB
    __shared__ float cvl[CH_R * 32 * CDIM];     // [rr][bb][cc] f32, 10 KB
    __shared__ float sts[32 * CDIM * 2];        // stats tile, 2.5 KB
    const int t = threadIdx.x;
    const int l = t & 63, w = t >> 6;
    const int b0 = blockIdx.x * 32;
    const int rg0 = blockIdx.y * R_PER_SPLIT;
    const int cbase = (w & 1) * 5;
    const int bsub = w >> 1;
    const int row = l & 15;
    const int kg = l >> 4;

    if (MODE == 1) {
        for (int e = t; e < 32 * CDIM * 2; e += 256)
            sts[e] = stats[(size_t)b0 * CDIM * 2 + e];
    }
    __syncthreads();

    f32x4 acc[5];
#pragma unroll
    for (int s = 0; s < 5; ++s) acc[s] = (f32x4){0.f, 0.f, 0.f, 0.f};

    for (int ch = 0; ch < R_PER_SPLIT / CH_R; ++ch) {
        const int r0c = rg0 + ch * CH_R;
        for (int e = t; e < 512; e += 256) {
            int rr = e >> 6, rem = e & 63, bb = rem >> 1, q = rem & 1;
            const float4 x4 = *(const float4*)(
                x + ((size_t)(b0 + bb) * RDIM + r0c + rr) * IDIM + q * 4);
            f16x4 h;
            h[0] = (half_t)x4.x; h[1] = (half_t)x4.y;
            h[2] = (half_t)x4.z; h[3] = (half_t)x4.w;
            *(f16x4*)&xs[(rr * 32 + bb) * IDIM + q * 4] = h;
        }
        if (MODE == 1) {
            // bl layout (C,B,R): 8 consecutive r per (bb,cc)
            for (int e = t; e < CH_R * 32 * CDIM; e += 256) {
                int bb = e / 80;
                int rem = e - bb * 80;
                int cc = rem >> 3, rr = rem & 7;
                float bv = bl[((size_t)cc * BDIM + b0 + bb) * RDIM + r0c + rr];
                cvl[(rr * 32 + bb) * CDIM + cc] =
                    __expf(bv - sts[bb * 20 + cc * 2]) * sts[bb * 20 + cc * 2 + 1];
            }
        }
        __syncthreads();

#pragma unroll
        for (int rq = 0; rq < CH_R / 4; ++rq) {
            const int rr = rq * 4 + kg;
            const f16x8 xv = *(const f16x8*)&xs[(rr * 32 + bsub * 16 + row) * IDIM];
            const int rqg = (r0c >> 2) + rq;
#pragma unroll
            for (int s = 0; s < 5; ++s) {
                const int cc = cbase + s;
                float cval = (MODE == 1)
                    ? cvl[(rr * 32 + bsub * 16 + row) * CDIM + cc] : 1.0f;
                half_t chf = (half_t)cval;
                f16x8 av;
#pragma unroll
                for (int j = 0; j < 8; ++j) av[j] = xv[j] * chf;
                const f16x8 bv = *(const f16x8*)(
                    WF + ((size_t)(rqg * CDIM + cc) * 64 + l) * 8);
                acc[s] = __builtin_amdgcn_mfma_f32_16x16x32_f16(av, bv, acc[s], 0, 0, 0);
            }
        }
        __syncthreads();
    }

#pragma unroll
    for (int s = 0; s < 5; ++s) {
        const int cc = cbase + s;
#pragma unroll
        for (int reg = 0; reg < 4; ++reg) {
            float val = acc[s][reg];
            if (MODE == 0) val *= (1.0f / RDIM);
            int brow = b0 + bsub * 16 + kg * 4 + reg;
            s_part[((size_t)blockIdx.y * BDIM + brow) * CO + cc * ODIM + (l & 15)] = val;
        }
    }
}

// ---------------------------------------------------------------------------
// k_squash
// ---------------------------------------------------------------------------
__global__ __launch_bounds__(256) void k_squash(const float* __restrict__ s_part,
                                                float* __restrict__ dst) {
    int g = blockIdx.x * 256 + threadIdx.x;
    int b = g / CO;
    int co = g - b * CO;
    float s = 0.f;
#pragma unroll
    for (int p = 0; p < RSPLIT; ++p)
        s += s_part[((size_t)p * BDIM + b) * CO + co];
    float sq = s * s;
    sq += __shfl_xor(sq, 1, 16);
    sq += __shfl_xor(sq, 2, 16);
    sq += __shfl_xor(sq, 4, 16);
    sq += __shfl_xor(sq, 8, 16);
    float n = sq;
    float val = (n / (n + 1.0f)) * s / sqrtf(n);
    dst[g] = val;
}

// ---------------------------------------------------------------------------
// k_bT: bl[c][b][r] (+)= sum_i x[b,r,i] * T_c[r*8+i][b],
//       T_c[m][b] = sum_o W[r,i,c,o] v[b,c,o]  via mfma_f32_16x16x32_f16.
// Block 256 = 4 waves; wave w owns b sub-tile (b0 + w*16, 16 b's).
// r-tile 16 (= 128 M-rows = 8 m-tiles). Epilogue: 4 FMA + 1 shfl per lane,
// per-wave [16][17] transpose tile -> coalesced 64-B r-runs into bl (C,B,R).
// ---------------------------------------------------------------------------
template <int ACC>
__global__ __launch_bounds__(256) void k_bT(const float* __restrict__ x,
                                            const half_t* __restrict__ WA,
                                            const half_t* __restrict__ VF,
                                            float* __restrict__ bl) {
    __shared__ float xs[64][132];     // [b-local][r*8+i], +4 pad (33.8 KB)
    __shared__ float tt[4][16][17];   // per-wave transpose tile (4.3 KB)
    const int t = threadIdx.x, l = t & 63, w = t >> 6;
    const int b0 = blockIdx.x * 64, r0 = blockIdx.y * 16;
    const int row = l & 15, kg = l >> 4;

    // stage x: 64 b x 16 r x 8 i (f32), 2048 float4 loads, coalesced
    for (int e = t; e < 2048; e += 256) {
        int b = e >> 5, rem = e & 31, r = rem >> 1, q = (rem & 1) * 4;
        const float4 x4 = *(const float4*)(
            x + ((size_t)(b0 + b) * RDIM + r0 + r) * IDIM + q);
        *(float4*)&xs[b][r * 8 + q] = x4;
    }
    __syncthreads();

    const int bt = (b0 >> 4) + w;               // global b-tile for this wave
    for (int c = 0; c < 10; ++c) {
        const f16x8 bf = *(const f16x8*)(VF + ((size_t)(c * 64 + bt) * 64 + l) * 8);
#pragma unroll
        for (int mt = 0; mt < 8; ++mt) {
            const f16x8 af = *(const f16x8*)(
                WA + ((size_t)((blockIdx.y * 8 + mt) * 10 + c) * 64 + l) * 8);
            f32x4 d = {0.f, 0.f, 0.f, 0.f};
            d = __builtin_amdgcn_mfma_f32_16x16x32_f16(af, bf, d, 0, 0, 0);
            // D: col b = l&15, row m-local = kg*4+reg; r_loc = mt*2 + (kg>>1),
            // i = (kg&1)*4 + reg
            const int r_loc = mt * 2 + (kg >> 1);
            const float4 x4 = *(const float4*)&xs[w * 16 + row][r_loc * 8 + (kg & 1) * 4];
            float pv = d[0] * x4.x + d[1] * x4.y + d[2] * x4.z + d[3] * x4.w;
            pv += __shfl_xor(pv, 16, 64);       // fold i-halves (kg0+kg1, kg2+kg3)
            if (!(kg & 1)) tt[w][r_loc][row] = pv;
        }
        // copy out 16r x 16b: lane: bb = l>>2, rq = l&3 -> 64-B r-runs
        {
            const int bb = l >> 2, rq = l & 3;
            float4 o4;
            o4.x = tt[w][rq * 4 + 0][bb];
            o4.y = tt[w][rq * 4 + 1][bb];
            o4.z = tt[w][rq * 4 + 2][bb];
            o4.w = tt[w][rq * 4 + 3][bb];
            size_t gi = ((size_t)c * BDIM + b0 + w * 16 + bb) * RDIM + r0 + rq * 4;
            if (ACC) {
                const float4 old = *(const float4*)(bl + gi);
                o4.x += old.x; o4.y += old.y; o4.z += old.z; o4.w += old.w;
            }
            *(float4*)(bl + gi) = o4;
        }
    }
}

// ---------------------------------------------------------------------------
// k_stats: per (b,c): max over r of bl[c][b][:], and 1/sum(exp(.-max)).
// One wave per (b,c); 1152 = 18*64 contiguous floats.
// ---------------------------------------------------------------------------
__global__ __launch_bounds__(256) void k_stats(const float* __restrict__ bl,
                                               float* __restrict__ stats) {
    const int t = threadIdx.x, lane = t & 63, w = t >> 6;
    const int gw = blockIdx.x * 4 + w;          // b*10 + c
    const int b = gw / 10, c = gw - b * 10;
    const float* p = bl + ((size_t)c * BDIM + b) * RDIM;
    float rv[18];
#pragma unroll
    for (int s = 0; s < 18; ++s) rv[s] = p[lane + s * 64];
    float m = rv[0];
#pragma unroll
    for (int s = 1; s < 18; ++s) m = fmaxf(m, rv[s]);
    for (int d = 1; d < 64; d <<= 1) m = fmaxf(m, __shfl_xor(m, d, 64));
    float se = 0.f;
#pragma unroll
    for (int s = 0; s < 18; ++s) se += __expf(rv[s] - m);
    for (int d = 1; d < 64; d <<= 1) se += __shfl_xor(se, d, 64);
    if (lane == 0) {
        stats[(size_t)gw * 2 + 0] = m;
        stats[(size_t)gw * 2 + 1] = 1.0f / se;
    }
}

// ---------------------------------------------------------------------------
extern "C" void kernel_launch(void* const* d_in, const int* in_sizes, int n_in,
                              void* d_out, int out_size, void* d_ws, size_t ws_size,
                              hipStream_t stream) {
    const float* x = (const float*)d_in[0];
    const float* W = (const float*)d_in[1];
    float* out = (float*)d_out;
    float* ws = (float*)d_ws;

    float* bl = ws + OFF_BL;
    float* v  = ws + OFF_V;
    float* st = ws + OFF_ST;
    float* sp = ws + OFF_SP;
    half_t* wf = (half_t*)(ws + OFF_WF);
    half_t* wa = (half_t*)(ws + OFF_WA);
    half_t* vf = (half_t*)(ws + OFF_VF);

    dim3 gs(BDIM / 32, RSPLIT);                // 32 x 16 blocks of 256
    dim3 gb(BDIM / 64, RDIM / 16);             // 16 x 72 blocks of 256

    k_wprep<<<720, 256, 0, stream>>>(W, wf);
    k_wprep_T<<<1440, 256, 0, stream>>>(W, wa);

    // iteration 0: softmax(0) uniform -> s0 = mean_r u_hat
    k_s_mfma<0><<<gs, 256, 0, stream>>>(x, wf, bl, st, sp);
    k_squash<<<(BDIM * CO) / 256, 256, 0, stream>>>(sp, v);
    k_vprep<<<160, 256, 0, stream>>>(v, vf);
    k_bT<0><<<gb, 256, 0, stream>>>(x, wa, vf, bl);        // b1 = u_hat . v0

    // iteration 1
    k_stats<<<2560, 256, 0, stream>>>(bl, st);
    k_s_mfma<1><<<gs, 256, 0, stream>>>(x, wf, bl, st, sp);
    k_squash<<<(BDIM * CO) / 256, 256, 0, stream>>>(sp, v);
    k_vprep<<<160, 256, 0, stream>>>(v, vf);
    k_bT<1><<<gb, 256, 0, stream>>>(x, wa, vf, bl);        // b2 = b1 + u_hat . v1

    // iteration 2 (final; no b update)
    k_stats<<<2560, 256, 0, stream>>>(bl, st);
    k_s_mfma<1><<<gs, 256, 0, stream>>>(x, wf, bl, st, sp);
    k_squash<<<(BDIM * CO) / 256, 256, 0, stream>>>(sp, out);
}

// Round 11
// 244.969 us; speedup vs baseline: 3.1211x; 1.3762x over previous
//
#include <hip/hip_runtime.h>
#include <math.h>

// Problem dims
#define BDIM 1024
#define RDIM 1152
#define IDIM 8
#define CDIM 10
#define ODIM 16
#define CO   160   // CDIM*ODIM

typedef _Float16 half_t;
typedef half_t f16x4 __attribute__((ext_vector_type(4)));
typedef half_t f16x8 __attribute__((ext_vector_type(8)));
typedef float  f32x4 __attribute__((ext_vector_type(4)));

constexpr int RSPLIT = 24;                      // r splits in k_s (1152/24 = 48)
constexpr int R_PER_SPLIT = RDIM / RSPLIT;      // 48
constexpr int CH_R = 8;                         // r chunk per stage (2 MFMA k-steps)

// workspace layout (in float units)
// bl stored TRANSPOSED: (C, B, R) -> k_bT writes r-runs, k_stats reads rows
constexpr size_t OFF_BL = 0;
constexpr size_t SZ_BL  = (size_t)BDIM * RDIM * CDIM;         // 11,796,480
constexpr size_t OFF_V  = OFF_BL + SZ_BL;                     // v (B,C,O)
constexpr size_t SZ_V   = (size_t)BDIM * CO;
constexpr size_t OFF_ST = OFF_V + SZ_V;                       // stats (B,C,2)
constexpr size_t SZ_ST  = (size_t)BDIM * CDIM * 2;
constexpr size_t OFF_SP = OFF_ST + SZ_ST;                     // s partials
constexpr size_t SZ_SP  = (size_t)RSPLIT * BDIM * CO;         // 3,932,160
constexpr size_t OFF_WF = OFF_SP + SZ_SP;                     // k_s W frags (f16)
constexpr size_t SZ_WF  = 737280;                             // 184320*8 f16
constexpr size_t OFF_WA = OFF_WF + SZ_WF;                     // k_bT A frags (f16)
constexpr size_t SZ_WA  = 1474560;                            // 368640*8 f16 / 2
constexpr size_t OFF_VF = OFF_WA + SZ_WA;                     // k_bT B frags (f16)
constexpr size_t SZ_VF  = 163840;                             // 40960*8 f16 / 2
constexpr size_t OFF_VC = OFF_VF + SZ_VF;                     // v cumulative (f32)
constexpr size_t SZ_VC  = (size_t)BDIM * CO;                  // 163,840
// total ~18.5M floats = 73.9 MB

// ---------------------------------------------------------------------------
// k_wprep: W (R,I,C,O) f32 -> fragment-ordered f16 for k_s's B operand (K=32).
// WF[((rq*10+c)*64+l)*8 + j] = (f16) W[rq*4 + (l>>4)][i=j][c][o=l&15]
// ---------------------------------------------------------------------------
__global__ __launch_bounds__(256) void k_wprep(const float* __restrict__ W,
                                               half_t* __restrict__ WF) {
    int g = blockIdx.x * 256 + threadIdx.x;    // 184320
    int lane = g & 63;
    int rc = g >> 6;
    int c = rc % 10;
    int rq = rc / 10;
    int r = rq * 4 + (lane >> 4);
    int o = lane & 15;
    const float* wp = W + (size_t)r * IDIM * CO + c * ODIM + o;
    f16x8 v;
#pragma unroll
    for (int j = 0; j < 8; ++j) v[j] = (half_t)wp[(size_t)j * CO];
    *(f16x8*)(WF + (size_t)g * 8) = v;
}

// ---------------------------------------------------------------------------
// k_wprep_T: A-frags for k_bT's T-GEMM.  A[m=(r,i)][k=o] per c, K padded to 32.
// WA[((mt*10+c)*64 + l)*8 + j]:
//   row = l&15, m = mt*16+row, r = m>>3, i = m&7, kg = l>>4
//   kg<2: (f16) W[r][i][c][o=kg*8+j] ; kg>=2: 0
// ---------------------------------------------------------------------------
__global__ __launch_bounds__(256) void k_wprep_T(const float* __restrict__ W,
                                                 half_t* __restrict__ WA) {
    int g = blockIdx.x * 256 + threadIdx.x;    // 576*10*64 = 368640
    int l = g & 63;
    int mc = g >> 6;
    int c = mc % 10;
    int mt = mc / 10;
    int m = mt * 16 + (l & 15);
    int r = m >> 3, i = m & 7, kg = l >> 4;
    f16x8 v = {0, 0, 0, 0, 0, 0, 0, 0};
    if (kg < 2) {
        const float* wp = W + (size_t)r * 1280 + i * 160 + c * 16 + kg * 8;
#pragma unroll
        for (int j = 0; j < 8; ++j) v[j] = (half_t)wp[j];
    }
    *(f16x8*)(WA + (size_t)g * 8) = v;
}

// ---------------------------------------------------------------------------
// k_vprep<FIRST>: maintain v_cum (prefix sum of v over iterations) and emit
// B-frags of v_cum for k_bT.  b_k = u_hat . (v_0+...+v_{k-1})  => no bl RMW.
// Each v_cum element is owned by exactly one thread (bijection) -> safe RMW.
// VF[((c*64+bt)*64 + l)*8 + j]: l<32: (f16) vcum[bt*16+(l&15)][c][(l>>4)*8+j]; else 0
// ---------------------------------------------------------------------------
template <int FIRST>
__global__ __launch_bounds__(256) void k_vprep(const float* __restrict__ v,
                                               float* __restrict__ vcum,
                                               half_t* __restrict__ VF) {
    int g = blockIdx.x * 256 + threadIdx.x;    // 10*64*64 = 40960
    int l = g & 63;
    int cb = g >> 6;
    int bt = cb & 63;
    int c = cb >> 6;
    f16x8 h = {0, 0, 0, 0, 0, 0, 0, 0};
    if (l < 32) {
        const size_t vidx = (size_t)(bt * 16 + (l & 15)) * CO + c * 16 + (l >> 4) * 8;
#pragma unroll
        for (int j = 0; j < 8; ++j) {
            float val = v[vidx + j];
            if (!FIRST) val += vcum[vidx + j];
            vcum[vidx + j] = val;
            h[j] = (half_t)val;
        }
    }
    *(f16x8*)(VF + (size_t)g * 8) = h;
}

// ---------------------------------------------------------------------------
// k_s_mfma: s_part[split][b][c][o] = sum_{r in split} cval(b,r,c)*u_hat(b,r,c,o)
// ---------------------------------------------------------------------------
template <int MODE>
__global__ __launch_bounds__(256) void k_s_mfma(const float* __restrict__ x,
                                                const half_t* __restrict__ WF,
                                                const float* __restrict__ bl,
                                                const float* __restrict__ stats,
                                                float* __restrict__ s_part) {
    __shared__ half_t xs[CH_R * 32 * IDIM];     // [rr][bb][i] f16, 4 KB
    __shared__ float cvl[CH_R * 32 * CDIM];     // [rr][bb][cc] f32, 10 KB
    __shared__ float sts[32 * CDIM * 2];        // stats tile, 2.5 KB
    const int t = threadIdx.x;
    const int l = t & 63, w = t >> 6;
    const int b0 = blockIdx.x * 32;
    const int rg0 = blockIdx.y * R_PER_SPLIT;
    const int cbase = (w & 1) * 5;
    const int bsub = w >> 1;
    const int row = l & 15;
    const int kg = l >> 4;

    if (MODE == 1) {
        for (int e = t; e < 32 * CDIM * 2; e += 256)
            sts[e] = stats[(size_t)b0 * CDIM * 2 + e];
    }
    __syncthreads();

    f32x4 acc[5];
#pragma unroll
    for (int s = 0; s < 5; ++s) acc[s] = (f32x4){0.f, 0.f, 0.f, 0.f};

    for (int ch = 0; ch < R_PER_SPLIT / CH_R; ++ch) {
        const int r0c = rg0 + ch * CH_R;
        for (int e = t; e < 512; e += 256) {
            int rr = e >> 6, rem = e & 63, bb = rem >> 1, q = rem & 1;
            const float4 x4 = *(const float4*)(
                x + ((size_t)(b0 + bb) * RDIM + r0c + rr) * IDIM + q * 4);
            f16x4 h;
            h[0] = (half_t)x4.x; h[1] = (half_t)x4.y;
            h[2] = (half_t)x4.z; h[3] = (half_t)x4.w;
            *(f16x4*)&xs[(rr * 32 + bb) * IDIM + q * 4] = h;
        }
        if (MODE == 1) {
            // bl layout (C,B,R): 8 consecutive r per (bb,cc)
            for (int e = t; e < CH_R * 32 * CDIM; e += 256) {
                int bb = e / 80;
                int rem = e - bb * 80;
                int cc = rem >> 3, rr = rem & 7;
                float bv = bl[((size_t)cc * BDIM + b0 + bb) * RDIM + r0c + rr];
                cvl[(rr * 32 + bb) * CDIM + cc] =
                    __expf(bv - sts[bb * 20 + cc * 2]) * sts[bb * 20 + cc * 2 + 1];
            }
        }
        __syncthreads();

#pragma unroll
        for (int rq = 0; rq < CH_R / 4; ++rq) {
            const int rr = rq * 4 + kg;
            const f16x8 xv = *(const f16x8*)&xs[(rr * 32 + bsub * 16 + row) * IDIM];
            const int rqg = (r0c >> 2) + rq;
#pragma unroll
            for (int s = 0; s < 5; ++s) {
                const int cc = cbase + s;
                float cval = (MODE == 1)
                    ? cvl[(rr * 32 + bsub * 16 + row) * CDIM + cc] : 1.0f;
                half_t chf = (half_t)cval;
                f16x8 av;
#pragma unroll
                for (int j = 0; j < 8; ++j) av[j] = xv[j] * chf;
                const f16x8 bv = *(const f16x8*)(
                    WF + ((size_t)(rqg * CDIM + cc) * 64 + l) * 8);
                acc[s] = __builtin_amdgcn_mfma_f32_16x16x32_f16(av, bv, acc[s], 0, 0, 0);
            }
        }
        __syncthreads();
    }

#pragma unroll
    for (int s = 0; s < 5; ++s) {
        const int cc = cbase + s;
#pragma unroll
        for (int reg = 0; reg < 4; ++reg) {
            float val = acc[s][reg];
            if (MODE == 0) val *= (1.0f / RDIM);
            int brow = b0 + bsub * 16 + kg * 4 + reg;
            s_part[((size_t)blockIdx.y * BDIM + brow) * CO + cc * ODIM + (l & 15)] = val;
        }
    }
}

// ---------------------------------------------------------------------------
// k_squash
// ---------------------------------------------------------------------------
__global__ __launch_bounds__(256) void k_squash(const float* __restrict__ s_part,
                                                float* __restrict__ dst) {
    int g = blockIdx.x * 256 + threadIdx.x;
    int b = g / CO;
    int co = g - b * CO;
    float s = 0.f;
#pragma unroll
    for (int p = 0; p < RSPLIT; ++p)
        s += s_part[((size_t)p * BDIM + b) * CO + co];
    float sq = s * s;
    sq += __shfl_xor(sq, 1, 16);
    sq += __shfl_xor(sq, 2, 16);
    sq += __shfl_xor(sq, 4, 16);
    sq += __shfl_xor(sq, 8, 16);
    float n = sq;
    float val = (n / (n + 1.0f)) * s / sqrtf(n);
    dst[g] = val;
}

// ---------------------------------------------------------------------------
// k_bT: bl[c][b][r] = sum_i x[b,r,i] * T_c[r*8+i][b],
//       T_c[m][b] = sum_o W[r,i,c,o] vcum[b,c,o]  via mfma_f32_16x16x32_f16.
// No bl read (prefix-sum v_cum trick). xs staged f16 -> 21.8 KB LDS total,
// ~7 blocks/CU residency (was 2 at f32/38.4 KB).
// Block 256 = 4 waves; wave w owns b sub-tile (b0 + w*16, 16 b's).
// r-tile 16 (= 128 M-rows = 8 m-tiles). Epilogue: 4 FMA + 1 shfl per lane,
// per-wave [16][17] transpose tile -> coalesced 64-B r-runs into bl (C,B,R).
// ---------------------------------------------------------------------------
__global__ __launch_bounds__(256) void k_bT(const float* __restrict__ x,
                                            const half_t* __restrict__ WA,
                                            const half_t* __restrict__ VF,
                                            float* __restrict__ bl) {
    __shared__ half_t xs[64][136];    // [b-local][r*8+i] f16, +8 pad (17.4 KB)
    __shared__ float tt[4][16][17];   // per-wave transpose tile (4.3 KB)
    const int t = threadIdx.x, l = t & 63, w = t >> 6;
    const int b0 = blockIdx.x * 64, r0 = blockIdx.y * 16;
    const int row = l & 15, kg = l >> 4;

    // stage x: 64 b x 16 r x 8 i (f32 -> f16), coalesced float4 loads
    for (int e = t; e < 2048; e += 256) {
        int b = e >> 5, rem = e & 31, r = rem >> 1, q = (rem & 1) * 4;
        const float4 x4 = *(const float4*)(
            x + ((size_t)(b0 + b) * RDIM + r0 + r) * IDIM + q);
        f16x4 h;
        h[0] = (half_t)x4.x; h[1] = (half_t)x4.y;
        h[2] = (half_t)x4.z; h[3] = (half_t)x4.w;
        *(f16x4*)&xs[b][r * 8 + q] = h;
    }
    __syncthreads();

    const int bt = (b0 >> 4) + w;               // global b-tile for this wave
    for (int c = 0; c < 10; ++c) {
        const f16x8 bf = *(const f16x8*)(VF + ((size_t)(c * 64 + bt) * 64 + l) * 8);
#pragma unroll
        for (int mt = 0; mt < 8; ++mt) {
            const f16x8 af = *(const f16x8*)(
                WA + ((size_t)((blockIdx.y * 8 + mt) * 10 + c) * 64 + l) * 8);
            f32x4 d = {0.f, 0.f, 0.f, 0.f};
            d = __builtin_amdgcn_mfma_f32_16x16x32_f16(af, bf, d, 0, 0, 0);
            // D: col b = l&15, row m-local = kg*4+reg; r_loc = mt*2 + (kg>>1),
            // i = (kg&1)*4 + reg
            const int r_loc = mt * 2 + (kg >> 1);
            const f16x4 xh = *(const f16x4*)&xs[w * 16 + row][r_loc * 8 + (kg & 1) * 4];
            float pv = d[0] * (float)xh[0] + d[1] * (float)xh[1] +
                       d[2] * (float)xh[2] + d[3] * (float)xh[3];
            pv += __shfl_xor(pv, 16, 64);       // fold i-halves (kg0+kg1, kg2+kg3)
            if (!(kg & 1)) tt[w][r_loc][row] = pv;
        }
        // copy out 16r x 16b: lane: bb = l>>2, rq = l&3 -> 64-B r-runs
        {
            const int bb = l >> 2, rq = l & 3;
            float4 o4;
            o4.x = tt[w][rq * 4 + 0][bb];
            o4.y = tt[w][rq * 4 + 1][bb];
            o4.z = tt[w][rq * 4 + 2][bb];
            o4.w = tt[w][rq * 4 + 3][bb];
            size_t gi = ((size_t)c * BDIM + b0 + w * 16 + bb) * RDIM + r0 + rq * 4;
            *(float4*)(bl + gi) = o4;
        }
    }
}

// ---------------------------------------------------------------------------
// k_stats: per (b,c): max over r of bl[c][b][:], and 1/sum(exp(.-max)).
// One wave per (b,c); 1152 = 18*64 contiguous floats.
// ---------------------------------------------------------------------------
__global__ __launch_bounds__(256) void k_stats(const float* __restrict__ bl,
                                               float* __restrict__ stats) {
    const int t = threadIdx.x, lane = t & 63, w = t >> 6;
    const int gw = blockIdx.x * 4 + w;          // b*10 + c
    const int b = gw / 10, c = gw - b * 10;
    const float* p = bl + ((size_t)c * BDIM + b) * RDIM;
    float rv[18];
#pragma unroll
    for (int s = 0; s < 18; ++s) rv[s] = p[lane + s * 64];
    float m = rv[0];
#pragma unroll
    for (int s = 1; s < 18; ++s) m = fmaxf(m, rv[s]);
    for (int d = 1; d < 64; d <<= 1) m = fmaxf(m, __shfl_xor(m, d, 64));
    float se = 0.f;
#pragma unroll
    for (int s = 0; s < 18; ++s) se += __expf(rv[s] - m);
    for (int d = 1; d < 64; d <<= 1) se += __shfl_xor(se, d, 64);
    if (lane == 0) {
        stats[(size_t)gw * 2 + 0] = m;
        stats[(size_t)gw * 2 + 1] = 1.0f / se;
    }
}

// ---------------------------------------------------------------------------
extern "C" void kernel_launch(void* const* d_in, const int* in_sizes, int n_in,
                              void* d_out, int out_size, void* d_ws, size_t ws_size,
                              hipStream_t stream) {
    const float* x = (const float*)d_in[0];
    const float* W = (const float*)d_in[1];
    float* out = (float*)d_out;
    float* ws = (float*)d_ws;

    float* bl = ws + OFF_BL;
    float* v  = ws + OFF_V;
    float* st = ws + OFF_ST;
    float* sp = ws + OFF_SP;
    half_t* wf = (half_t*)(ws + OFF_WF);
    half_t* wa = (half_t*)(ws + OFF_WA);
    half_t* vf = (half_t*)(ws + OFF_VF);
    float* vc = ws + OFF_VC;

    dim3 gs(BDIM / 32, RSPLIT);                // 32 x 24 blocks of 256
    dim3 gb(BDIM / 64, RDIM / 16);             // 16 x 72 blocks of 256

    k_wprep<<<720, 256, 0, stream>>>(W, wf);
    k_wprep_T<<<1440, 256, 0, stream>>>(W, wa);

    // iteration 0: softmax(0) uniform -> s0 = mean_r u_hat
    k_s_mfma<0><<<gs, 256, 0, stream>>>(x, wf, bl, st, sp);
    k_squash<<<(BDIM * CO) / 256, 256, 0, stream>>>(sp, v);
    k_vprep<1><<<160, 256, 0, stream>>>(v, vc, vf);
    k_bT<<<gb, 256, 0, stream>>>(x, wa, vf, bl);           // b1 = u_hat . vcum

    // iteration 1
    k_stats<<<2560, 256, 0, stream>>>(bl, st);
    k_s_mfma<1><<<gs, 256, 0, stream>>>(x, wf, bl, st, sp);
    k_squash<<<(BDIM * CO) / 256, 256, 0, stream>>>(sp, v);
    k_vprep<0><<<160, 256, 0, stream>>>(v, vc, vf);
    k_bT<<<gb, 256, 0, stream>>>(x, wa, vf, bl);           // b2 = u_hat . vcum

    // iteration 2 (final; no b update)
    k_stats<<<2560, 256, 0, stream>>>(bl, st);
    k_s_mfma<1><<<gs, 256, 0, stream>>>(x, wf, bl, st, sp);
    k_squash<<<(BDIM * CO) / 256, 256, 0, stream>>>(sp, out);
}

// Round 12
// 217.817 us; speedup vs baseline: 3.5102x; 1.1247x over previous
//
#include <hip/hip_runtime.h>
#include <math.h>

// Problem dims
#define BDIM 1024
#define RDIM 1152
#define IDIM 8
#define CDIM 10
#define ODIM 16
#define CO   160   // CDIM*ODIM

typedef _Float16 half_t;
typedef half_t f16x4 __attribute__((ext_vector_type(4)));
typedef half_t f16x8 __attribute__((ext_vector_type(8)));
typedef float  f32x4 __attribute__((ext_vector_type(4)));

constexpr int RSPLIT = 48;                      // r splits in k_s (1152/48 = 24)
constexpr int R_PER_SPLIT = RDIM / RSPLIT;      // 24
constexpr int CH_R = 8;                         // r chunk per stage (2 MFMA k-steps)

// cvl LDS: addr = rr*324 + bb*10 + cc  (stride 324 = 4 mod 32 banks -> ~2-way)
constexpr int CVL_STRIDE = 324;
constexpr int CVL_SIZE = 7 * CVL_STRIDE + 31 * 10 + 10;   // 2588 floats

// workspace layout (in float units)
// bl stored TRANSPOSED: (C, B, R) -> k_bT writes r-runs, k_stats reads rows
constexpr size_t OFF_BL = 0;
constexpr size_t SZ_BL  = (size_t)BDIM * RDIM * CDIM;         // 11,796,480
constexpr size_t OFF_V  = OFF_BL + SZ_BL;                     // v (B,C,O)
constexpr size_t SZ_V   = (size_t)BDIM * CO;
constexpr size_t OFF_ST = OFF_V + SZ_V;                       // stats (B,C,2)
constexpr size_t SZ_ST  = (size_t)BDIM * CDIM * 2;
constexpr size_t OFF_SP = OFF_ST + SZ_ST;                     // s partials
constexpr size_t SZ_SP  = (size_t)RSPLIT * BDIM * CO;         // 7,864,320
constexpr size_t OFF_WF = OFF_SP + SZ_SP;                     // k_s W frags (f16)
constexpr size_t SZ_WF  = 737280;                             // 184320*8 f16
constexpr size_t OFF_WA = OFF_WF + SZ_WF;                     // k_bT A frags (f16)
constexpr size_t SZ_WA  = 1474560;                            // 368640*8 f16 / 2
constexpr size_t OFF_VF = OFF_WA + SZ_WA;                     // k_bT B frags (f16)
constexpr size_t SZ_VF  = 163840;                             // 40960*8 f16 / 2
constexpr size_t OFF_VC = OFF_VF + SZ_VF;                     // v cumulative (f32)
constexpr size_t SZ_VC  = (size_t)BDIM * CO;                  // 163,840
// total ~22.4M floats = 89.7 MB

// ---------------------------------------------------------------------------
// k_wprep: W (R,I,C,O) f32 -> fragment-ordered f16 for k_s's B operand (K=32).
// WF[((rq*10+c)*64+l)*8 + j] = (f16) W[rq*4 + (l>>4)][i=j][c][o=l&15]
// ---------------------------------------------------------------------------
__global__ __launch_bounds__(256) void k_wprep(const float* __restrict__ W,
                                               half_t* __restrict__ WF) {
    int g = blockIdx.x * 256 + threadIdx.x;    // 184320
    int lane = g & 63;
    int rc = g >> 6;
    int c = rc % 10;
    int rq = rc / 10;
    int r = rq * 4 + (lane >> 4);
    int o = lane & 15;
    const float* wp = W + (size_t)r * IDIM * CO + c * ODIM + o;
    f16x8 v;
#pragma unroll
    for (int j = 0; j < 8; ++j) v[j] = (half_t)wp[(size_t)j * CO];
    *(f16x8*)(WF + (size_t)g * 8) = v;
}

// ---------------------------------------------------------------------------
// k_wprep_T: A-frags for k_bT's T-GEMM.  A[m=(r,i)][k=o] per c, K padded to 32.
// WA[((mt*10+c)*64 + l)*8 + j]:
//   row = l&15, m = mt*16+row, r = m>>3, i = m&7, kg = l>>4
//   kg<2: (f16) W[r][i][c][o=kg*8+j] ; kg>=2: 0
// ---------------------------------------------------------------------------
__global__ __launch_bounds__(256) void k_wprep_T(const float* __restrict__ W,
                                                 half_t* __restrict__ WA) {
    int g = blockIdx.x * 256 + threadIdx.x;    // 576*10*64 = 368640
    int l = g & 63;
    int mc = g >> 6;
    int c = mc % 10;
    int mt = mc / 10;
    int m = mt * 16 + (l & 15);
    int r = m >> 3, i = m & 7, kg = l >> 4;
    f16x8 v = {0, 0, 0, 0, 0, 0, 0, 0};
    if (kg < 2) {
        const float* wp = W + (size_t)r * 1280 + i * 160 + c * 16 + kg * 8;
#pragma unroll
        for (int j = 0; j < 8; ++j) v[j] = (half_t)wp[j];
    }
    *(f16x8*)(WA + (size_t)g * 8) = v;
}

// ---------------------------------------------------------------------------
// k_vprep<FIRST>: maintain v_cum (prefix sum of v over iterations) and emit
// B-frags of v_cum for k_bT.  b_k = u_hat . (v_0+...+v_{k-1})  => no bl RMW.
// VF[((c*64+bt)*64 + l)*8 + j]: l<32: (f16) vcum[bt*16+(l&15)][c][(l>>4)*8+j]; else 0
// ---------------------------------------------------------------------------
template <int FIRST>
__global__ __launch_bounds__(256) void k_vprep(const float* __restrict__ v,
                                               float* __restrict__ vcum,
                                               half_t* __restrict__ VF) {
    int g = blockIdx.x * 256 + threadIdx.x;    // 10*64*64 = 40960
    int l = g & 63;
    int cb = g >> 6;
    int bt = cb & 63;
    int c = cb >> 6;
    f16x8 h = {0, 0, 0, 0, 0, 0, 0, 0};
    if (l < 32) {
        const size_t vidx = (size_t)(bt * 16 + (l & 15)) * CO + c * 16 + (l >> 4) * 8;
#pragma unroll
        for (int j = 0; j < 8; ++j) {
            float val = v[vidx + j];
            if (!FIRST) val += vcum[vidx + j];
            vcum[vidx + j] = val;
            h[j] = (half_t)val;
        }
    }
    *(f16x8*)(VF + (size_t)g * 8) = h;
}

// ---------------------------------------------------------------------------
// k_s_mfma: s_part[split][b][c][o] = sum_{r in split} cval(b,r,c)*u_hat(b,r,c,o)
// ---------------------------------------------------------------------------
template <int MODE>
__global__ __launch_bounds__(256) void k_s_mfma(const float* __restrict__ x,
                                                const half_t* __restrict__ WF,
                                                const float* __restrict__ bl,
                                                const float* __restrict__ stats,
                                                float* __restrict__ s_part) {
    __shared__ half_t xs[CH_R * 32 * IDIM];     // [rr][bb][i] f16, 4 KB
    __shared__ float cvl[CVL_SIZE];             // softmax coeffs, 10.4 KB
    __shared__ float sts[32 * CDIM * 2];        // stats tile, 2.5 KB
    const int t = threadIdx.x;
    const int l = t & 63, w = t >> 6;
    const int b0 = blockIdx.x * 32;
    const int rg0 = blockIdx.y * R_PER_SPLIT;
    const int cbase = (w & 1) * 5;
    const int bsub = w >> 1;
    const int row = l & 15;
    const int kg = l >> 4;

    if (MODE == 1) {
        for (int e = t; e < 32 * CDIM * 2; e += 256)
            sts[e] = stats[(size_t)b0 * CDIM * 2 + e];
    }
    __syncthreads();

    f32x4 acc[5];
#pragma unroll
    for (int s = 0; s < 5; ++s) acc[s] = (f32x4){0.f, 0.f, 0.f, 0.f};

    for (int ch = 0; ch < R_PER_SPLIT / CH_R; ++ch) {
        const int r0c = rg0 + ch * CH_R;
        for (int e = t; e < 512; e += 256) {
            int rr = e >> 6, rem = e & 63, bb = rem >> 1, q = rem & 1;
            const float4 x4 = *(const float4*)(
                x + ((size_t)(b0 + bb) * RDIM + r0c + rr) * IDIM + q * 4);
            f16x4 h;
            h[0] = (half_t)x4.x; h[1] = (half_t)x4.y;
            h[2] = (half_t)x4.z; h[3] = (half_t)x4.w;
            *(f16x4*)&xs[(rr * 32 + bb) * IDIM + q * 4] = h;
        }
        if (MODE == 1) {
            // bl layout (C,B,R): rr-fast mapping keeps 8-float global r-runs;
            // LDS banks = (4rr + 10bb + cc) mod 32  -> ~2-way
            for (int e = t; e < CH_R * 32 * CDIM; e += 256) {
                int bb = e / 80;
                int rem = e - bb * 80;
                int cc = rem >> 3, rr = rem & 7;
                float bv = bl[((size_t)cc * BDIM + b0 + bb) * RDIM + r0c + rr];
                cvl[rr * CVL_STRIDE + bb * 10 + cc] =
                    __expf(bv - sts[bb * 20 + cc * 2]) * sts[bb * 20 + cc * 2 + 1];
            }
        }
        __syncthreads();

#pragma unroll
        for (int rq = 0; rq < CH_R / 4; ++rq) {
            const int rr = rq * 4 + kg;
            const f16x8 xv = *(const f16x8*)&xs[(rr * 32 + bsub * 16 + row) * IDIM];
            const int rqg = (r0c >> 2) + rq;
#pragma unroll
            for (int s = 0; s < 5; ++s) {
                const int cc = cbase + s;
                float cval = (MODE == 1)
                    ? cvl[rr * CVL_STRIDE + (bsub * 16 + row) * 10 + cc] : 1.0f;
                half_t chf = (half_t)cval;
                f16x8 av;
#pragma unroll
                for (int j = 0; j < 8; ++j) av[j] = xv[j] * chf;
                const f16x8 bv = *(const f16x8*)(
                    WF + ((size_t)(rqg * CDIM + cc) * 64 + l) * 8);
                acc[s] = __builtin_amdgcn_mfma_f32_16x16x32_f16(av, bv, acc[s], 0, 0, 0);
            }
        }
        __syncthreads();
    }

#pragma unroll
    for (int s = 0; s < 5; ++s) {
        const int cc = cbase + s;
#pragma unroll
        for (int reg = 0; reg < 4; ++reg) {
            float val = acc[s][reg];
            if (MODE == 0) val *= (1.0f / RDIM);
            int brow = b0 + bsub * 16 + kg * 4 + reg;
            s_part[((size_t)blockIdx.y * BDIM + brow) * CO + cc * ODIM + (l & 15)] = val;
        }
    }
}

// ---------------------------------------------------------------------------
// k_squash
// ---------------------------------------------------------------------------
__global__ __launch_bounds__(256) void k_squash(const float* __restrict__ s_part,
                                                float* __restrict__ dst) {
    int g = blockIdx.x * 256 + threadIdx.x;
    int b = g / CO;
    int co = g - b * CO;
    float s = 0.f;
#pragma unroll
    for (int p = 0; p < RSPLIT; ++p)
        s += s_part[((size_t)p * BDIM + b) * CO + co];
    float sq = s * s;
    sq += __shfl_xor(sq, 1, 16);
    sq += __shfl_xor(sq, 2, 16);
    sq += __shfl_xor(sq, 4, 16);
    sq += __shfl_xor(sq, 8, 16);
    float n = sq;
    float val = (n / (n + 1.0f)) * s / sqrtf(n);
    dst[g] = val;
}

// ---------------------------------------------------------------------------
// k_bT: bl[c][b][r] = sum_i x[b,r,i] * T_c[r*8+i][b],
//       T_c[m][b] = sum_o W[r,i,c,o] vcum[b,c,o]  via mfma_f32_16x16x32_f16.
// No bl read (prefix-sum v_cum trick). xs staged f16 (21.8 KB LDS total).
// ---------------------------------------------------------------------------
__global__ __launch_bounds__(256) void k_bT(const float* __restrict__ x,
                                            const half_t* __restrict__ WA,
                                            const half_t* __restrict__ VF,
                                            float* __restrict__ bl) {
    __shared__ half_t xs[64][136];    // [b-local][r*8+i] f16, +8 pad (17.4 KB)
    __shared__ float tt[4][16][17];   // per-wave transpose tile (4.3 KB)
    const int t = threadIdx.x, l = t & 63, w = t >> 6;
    const int b0 = blockIdx.x * 64, r0 = blockIdx.y * 16;
    const int row = l & 15, kg = l >> 4;

    // stage x: 64 b x 16 r x 8 i (f32 -> f16), coalesced float4 loads
    for (int e = t; e < 2048; e += 256) {
        int b = e >> 5, rem = e & 31, r = rem >> 1, q = (rem & 1) * 4;
        const float4 x4 = *(const float4*)(
            x + ((size_t)(b0 + b) * RDIM + r0 + r) * IDIM + q);
        f16x4 h;
        h[0] = (half_t)x4.x; h[1] = (half_t)x4.y;
        h[2] = (half_t)x4.z; h[3] = (half_t)x4.w;
        *(f16x4*)&xs[b][r * 8 + q] = h;
    }
    __syncthreads();

    const int bt = (b0 >> 4) + w;               // global b-tile for this wave
    for (int c = 0; c < 10; ++c) {
        const f16x8 bf = *(const f16x8*)(VF + ((size_t)(c * 64 + bt) * 64 + l) * 8);
#pragma unroll
        for (int mt = 0; mt < 8; ++mt) {
            const f16x8 af = *(const f16x8*)(
                WA + ((size_t)((blockIdx.y * 8 + mt) * 10 + c) * 64 + l) * 8);
            f32x4 d = {0.f, 0.f, 0.f, 0.f};
            d = __builtin_amdgcn_mfma_f32_16x16x32_f16(af, bf, d, 0, 0, 0);
            // D: col b = l&15, row m-local = kg*4+reg; r_loc = mt*2 + (kg>>1),
            // i = (kg&1)*4 + reg
            const int r_loc = mt * 2 + (kg >> 1);
            const f16x4 xh = *(const f16x4*)&xs[w * 16 + row][r_loc * 8 + (kg & 1) * 4];
            float pv = d[0] * (float)xh[0] + d[1] * (float)xh[1] +
                       d[2] * (float)xh[2] + d[3] * (float)xh[3];
            pv += __shfl_xor(pv, 16, 64);       // fold i-halves (kg0+kg1, kg2+kg3)
            if (!(kg & 1)) tt[w][r_loc][row] = pv;
        }
        // copy out 16r x 16b: lane: bb = l>>2, rq = l&3 -> 64-B r-runs
        {
            const int bb = l >> 2, rq = l & 3;
            float4 o4;
            o4.x = tt[w][rq * 4 + 0][bb];
            o4.y = tt[w][rq * 4 + 1][bb];
            o4.z = tt[w][rq * 4 + 2][bb];
            o4.w = tt[w][rq * 4 + 3][bb];
            size_t gi = ((size_t)c * BDIM + b0 + w * 16 + bb) * RDIM + r0 + rq * 4;
            *(float4*)(bl + gi) = o4;
        }
    }
}

// ---------------------------------------------------------------------------
// k_stats: per (b,c): max over r of bl[c][b][:], and 1/sum(exp(.-max)).
// One wave per (b,c); 1152 = 18*64 contiguous floats.
// ---------------------------------------------------------------------------
__global__ __launch_bounds__(256) void k_stats(const float* __restrict__ bl,
                                               float* __restrict__ stats) {
    const int t = threadIdx.x, lane = t & 63, w = t >> 6;
    const int gw = blockIdx.x * 4 + w;          // b*10 + c
    const int b = gw / 10, c = gw - b * 10;
    const float* p = bl + ((size_t)c * BDIM + b) * RDIM;
    float rv[18];
#pragma unroll
    for (int s = 0; s < 18; ++s) rv[s] = p[lane + s * 64];
    float m = rv[0];
#pragma unroll
    for (int s = 1; s < 18; ++s) m = fmaxf(m, rv[s]);
    for (int d = 1; d < 64; d <<= 1) m = fmaxf(m, __shfl_xor(m, d, 64));
    float se = 0.f;
#pragma unroll
    for (int s = 0; s < 18; ++s) se += __expf(rv[s] - m);
    for (int d = 1; d < 64; d <<= 1) se += __shfl_xor(se, d, 64);
    if (lane == 0) {
        stats[(size_t)gw * 2 + 0] = m;
        stats[(size_t)gw * 2 + 1] = 1.0f / se;
    }
}

// ---------------------------------------------------------------------------
extern "C" void kernel_launch(void* const* d_in, const int* in_sizes, int n_in,
                              void* d_out, int out_size, void* d_ws, size_t ws_size,
                              hipStream_t stream) {
    const float* x = (const float*)d_in[0];
    const float* W = (const float*)d_in[1];
    float* out = (float*)d_out;
    float* ws = (float*)d_ws;

    float* bl = ws + OFF_BL;
    float* v  = ws + OFF_V;
    float* st = ws + OFF_ST;
    float* sp = ws + OFF_SP;
    half_t* wf = (half_t*)(ws + OFF_WF);
    half_t* wa = (half_t*)(ws + OFF_WA);
    half_t* vf = (half_t*)(ws + OFF_VF);
    float* vc = ws + OFF_VC;

    dim3 gs(BDIM / 32, RSPLIT);                // 32 x 48 blocks of 256
    dim3 gb(BDIM / 64, RDIM / 16);             // 16 x 72 blocks of 256

    k_wprep<<<720, 256, 0, stream>>>(W, wf);
    k_wprep_T<<<1440, 256, 0, stream>>>(W, wa);

    // iteration 0: softmax(0) uniform -> s0 = mean_r u_hat
    k_s_mfma<0><<<gs, 256, 0, stream>>>(x, wf, bl, st, sp);
    k_squash<<<(BDIM * CO) / 256, 256, 0, stream>>>(sp, v);
    k_vprep<1><<<160, 256, 0, stream>>>(v, vc, vf);
    k_bT<<<gb, 256, 0, stream>>>(x, wa, vf, bl);           // b1 = u_hat . vcum

    // iteration 1
    k_stats<<<2560, 256, 0, stream>>>(bl, st);
    k_s_mfma<1><<<gs, 256, 0, stream>>>(x, wf, bl, st, sp);
    k_squash<<<(BDIM * CO) / 256, 256, 0, stream>>>(sp, v);
    k_vprep<0><<<160, 256, 0, stream>>>(v, vc, vf);
    k_bT<<<gb, 256, 0, stream>>>(x, wa, vf, bl);           // b2 = u_hat . vcum

    // iteration 2 (final; no b update)
    k_stats<<<2560, 256, 0, stream>>>(bl, st);
    k_s_mfma<1><<<gs, 256, 0, stream>>>(x, wf, bl, st, sp);
    k_squash<<<(BDIM * CO) / 256, 256, 0, stream>>>(sp, out);
}